// Round 1
// baseline (443.014 us; speedup 1.0000x reference)
//
#include <hip/hip_runtime.h>
#include <stdint.h>

#define S_DIM 8192
#define K_DIM 4096
#define N_DIM 4096

#define BM 128
#define BN 128
#define BK 64

typedef int v4i __attribute__((ext_vector_type(4)));

// ---------------------------------------------------------------------------
// Pack int32-widened int8 values down to contiguous int8.
// Each thread handles 16 elements: 4x int4 loads (64B) -> one 16B store.
__global__ void pack_i8(const int* __restrict__ src, signed char* __restrict__ dst,
                        int n16) {
    int i = blockIdx.x * blockDim.x + threadIdx.x;
    if (i >= n16) return;
    const int4* s4 = (const int4*)src;
    int4 a = s4[i * 4 + 0];
    int4 b = s4[i * 4 + 1];
    int4 c = s4[i * 4 + 2];
    int4 d = s4[i * 4 + 3];
    int4 p;
    p.x = (a.x & 0xFF) | ((a.y & 0xFF) << 8) | ((a.z & 0xFF) << 16) | ((a.w & 0xFF) << 24);
    p.y = (b.x & 0xFF) | ((b.y & 0xFF) << 8) | ((b.z & 0xFF) << 16) | ((b.w & 0xFF) << 24);
    p.z = (c.x & 0xFF) | ((c.y & 0xFF) << 8) | ((c.z & 0xFF) << 16) | ((c.w & 0xFF) << 24);
    p.w = (d.x & 0xFF) | ((d.y & 0xFF) << 8) | ((d.z & 0xFF) << 16) | ((d.w & 0xFF) << 24);
    ((int4*)dst)[i] = p;
}

// ---------------------------------------------------------------------------
// scale_y passthrough (second tuple output, concatenated after out_q).
__global__ void copy_sy(const float* __restrict__ sy, float* __restrict__ out) {
    int i = blockIdx.x * blockDim.x + threadIdx.x;
    if (i < S_DIM) out[(size_t)S_DIM * N_DIM + i] = sy[i];
}

// ---------------------------------------------------------------------------
// async global->LDS, 16B per lane. LDS dest must be wave-uniform base + lane*16.
__device__ __forceinline__ void g2lds16(const void* g, void* l) {
    __builtin_amdgcn_global_load_lds((const __attribute__((address_space(1))) void*)g,
                                     (__attribute__((address_space(3))) void*)l,
                                     16, 0, 0);
}

// ---------------------------------------------------------------------------
// 128x128 tile i8 MFMA GEMM, B^T input (both operands K-major).
// 256 threads = 4 waves in 2x2; each wave computes 64x64 via 4x4 tiles of
// mfma_i32_16x16x64_i8. Staging: global_load_lds width=16.
__launch_bounds__(256)
__global__ void gemm_i8(const signed char* __restrict__ xp,
                        const signed char* __restrict__ wp,
                        const float* __restrict__ sx,
                        const float* __restrict__ sw,
                        const float* __restrict__ sy,
                        float* __restrict__ out) {
    __shared__ __align__(16) signed char As[BM * BK];   // [row][k], stride 64B
    __shared__ __align__(16) signed char Bs[BN * BK];   // [col][k], stride 64B

    const int tid  = threadIdx.x;
    const int lane = tid & 63;
    const int quad = lane >> 4;    // 0..3 -> k-group of 16 bytes
    const int l16  = lane & 15;    // row (A) / col (B) within 16
    const int wave = tid >> 6;     // 0..3
    const int wm = wave >> 1;      // wave row (2x2)
    const int wn = wave & 1;       // wave col
    const int bm = blockIdx.y;
    const int bn = blockIdx.x;

    const signed char* aG = xp + (size_t)(bm * BM) * K_DIM;
    const signed char* bG = wp + (size_t)(bn * BN) * K_DIM;

    v4i acc[4][4];
#pragma unroll
    for (int i = 0; i < 4; i++)
#pragma unroll
        for (int j = 0; j < 4; j++) acc[i][j] = 0;

    for (int kk = 0; kk < K_DIM; kk += BK) {
        __syncthreads();  // protect LDS from previous iteration's readers
#pragma unroll
        for (int i = 0; i < 2; i++) {
            // linear chunk index: 512 chunks of 16B per operand tile
            int li  = i * 256 + tid;
            int row = li >> 2;            // tile row (0..127)
            int ch  = (li & 3) << 4;      // 16B chunk within the 64B k-slice
            g2lds16(aG + (size_t)row * K_DIM + kk + ch, As + li * 16);
            g2lds16(bG + (size_t)row * K_DIM + kk + ch, Bs + li * 16);
        }
        __syncthreads();  // compiler inserts s_waitcnt vmcnt(0) before barrier

        v4i af[4], bf[4];
#pragma unroll
        for (int t = 0; t < 4; t++) {
            af[t] = *(const v4i*)(As + (wm * 64 + t * 16 + l16) * BK + quad * 16);
            bf[t] = *(const v4i*)(Bs + (wn * 64 + t * 16 + l16) * BK + quad * 16);
        }
#pragma unroll
        for (int mt = 0; mt < 4; mt++)
#pragma unroll
            for (int nt = 0; nt < 4; nt++)
                acc[mt][nt] = __builtin_amdgcn_mfma_i32_16x16x64_i8(
                    af[mt], bf[nt], acc[mt][nt], 0, 0, 0);
    }

    // Epilogue: C/D layout (verified): col = lane&15, row = quad*4 + reg.
    const int s_base = bm * BM + wm * 64;
    const int n_base = bn * BN + wn * 64;
#pragma unroll
    for (int mt = 0; mt < 4; mt++) {
#pragma unroll
        for (int r = 0; r < 4; r++) {
            int s = s_base + mt * 16 + quad * 4 + r;
            float rs = sx[s] / sy[s];
            float* orow = out + (size_t)s * N_DIM;
#pragma unroll
            for (int nt = 0; nt < 4; nt++) {
                int n = n_base + nt * 16 + l16;
                float v = rintf((float)acc[mt][nt][r] * (rs * sw[n]));
                v = fminf(fmaxf(v, -128.f), 127.f);
                orow[n] = v;
            }
        }
    }
}

// ---------------------------------------------------------------------------
// Correctness fallback if the workspace is too small for packed operands.
__global__ void gemm_naive(const int* __restrict__ x, const int* __restrict__ w,
                           const float* __restrict__ sx, const float* __restrict__ sw,
                           const float* __restrict__ sy, float* __restrict__ out) {
    int n = blockIdx.x * blockDim.x + threadIdx.x;
    int s = blockIdx.y;
    const int4* xr = (const int4*)(x + (size_t)s * K_DIM);
    const int4* wr = (const int4*)(w + (size_t)n * K_DIM);
    int acc = 0;
    for (int k = 0; k < K_DIM / 4; k++) {
        int4 a = xr[k], b = wr[k];
        acc += a.x * b.x + a.y * b.y + a.z * b.z + a.w * b.w;
    }
    float v = rintf((float)acc * (sx[s] / sy[s] * sw[n]));
    out[(size_t)s * N_DIM + n] = fminf(fmaxf(v, -128.f), 127.f);
}

// ---------------------------------------------------------------------------
extern "C" void kernel_launch(void* const* d_in, const int* in_sizes, int n_in,
                              void* d_out, int out_size, void* d_ws, size_t ws_size,
                              hipStream_t stream) {
    const int*   x  = (const int*)d_in[0];     // [S, K] int8 values widened to int32
    const int*   wq = (const int*)d_in[1];     // [N, K]
    const float* sx = (const float*)d_in[2];   // [S]
    const float* sw = (const float*)d_in[3];   // [N]
    const float* sy = (const float*)d_in[4];   // [S]
    float* out = (float*)d_out;                // [S*N out_q] ++ [S scale_y], float32

    copy_sy<<<dim3((S_DIM + 255) / 256), dim3(256), 0, stream>>>(sy, out);

    const size_t need = (size_t)S_DIM * K_DIM + (size_t)N_DIM * K_DIM;  // 48 MiB
    if (ws_size >= need) {
        signed char* xp = (signed char*)d_ws;
        signed char* wp = xp + (size_t)S_DIM * K_DIM;
        pack_i8<<<dim3(S_DIM * K_DIM / 16 / 256), dim3(256), 0, stream>>>(
            x, xp, S_DIM * K_DIM / 16);
        pack_i8<<<dim3(N_DIM * K_DIM / 16 / 256), dim3(256), 0, stream>>>(
            wq, wp, N_DIM * K_DIM / 16);
        gemm_i8<<<dim3(N_DIM / BN, S_DIM / BM), dim3(256), 0, stream>>>(
            xp, wp, sx, sw, sy, out);
    } else {
        gemm_naive<<<dim3(N_DIM / 256, S_DIM), dim3(256), 0, stream>>>(
            x, wq, sx, sw, sy, out);
    }
}

// Round 2
// 428.889 us; speedup vs baseline: 1.0329x; 1.0329x over previous
//
#include <hip/hip_runtime.h>
#include <stdint.h>

#define S_DIM 8192
#define K_DIM 4096
#define N_DIM 4096

#define BM 128
#define BN 128
#define BK 64

typedef int v4i __attribute__((ext_vector_type(4)));

// ---------------------------------------------------------------------------
// Pack int32-widened int8 values down to contiguous int8.
// One int4 load (16B/lane, unit inter-lane stride -> 1KiB coalesced per wave)
// and one packed dword store (4B/lane coalesced) per thread.
__global__ void pack_i8(const int* __restrict__ src, int* __restrict__ dst,
                        int n4) {
    int i = blockIdx.x * blockDim.x + threadIdx.x;
    if (i >= n4) return;
    int4 a = ((const int4*)src)[i];
    dst[i] = (a.x & 0xFF) | ((a.y & 0xFF) << 8) | ((a.z & 0xFF) << 16)
           | ((a.w & 0xFF) << 24);
}

// ---------------------------------------------------------------------------
// scale_y passthrough (second tuple output, concatenated after out_q).
__global__ void copy_sy(const float* __restrict__ sy, float* __restrict__ out) {
    int i = blockIdx.x * blockDim.x + threadIdx.x;
    if (i < S_DIM) out[(size_t)S_DIM * N_DIM + i] = sy[i];
}

// ---------------------------------------------------------------------------
// async global->LDS, 16B per lane. LDS dest must be wave-uniform base + lane*16.
__device__ __forceinline__ void g2lds16(const void* g, void* l) {
    __builtin_amdgcn_global_load_lds((const __attribute__((address_space(1))) void*)g,
                                     (__attribute__((address_space(3))) void*)l,
                                     16, 0, 0);
}

// ---------------------------------------------------------------------------
// 128x128 tile i8 MFMA GEMM, B^T input (both operands K-major).
// 256 threads = 4 waves in 2x2; each wave computes 64x64 via 4x4 tiles of
// mfma_i32_16x16x64_i8. Staging: global_load_lds width=16.
// LDS layout is XOR-swizzled: LDS[row][c] holds global 16B k-chunk
// (c ^ ((row>>1)&3)), making fragment ds_read_b128 2-way-per-bank (free)
// instead of 8-way.
__launch_bounds__(256)
__global__ void gemm_i8(const signed char* __restrict__ xp,
                        const signed char* __restrict__ wp,
                        const float* __restrict__ sx,
                        const float* __restrict__ sw,
                        const float* __restrict__ sy,
                        float* __restrict__ out) {
    __shared__ __align__(16) signed char As[BM * BK];   // [row][k], stride 64B
    __shared__ __align__(16) signed char Bs[BN * BK];   // [col][k], stride 64B

    const int tid  = threadIdx.x;
    const int lane = tid & 63;
    const int quad = lane >> 4;    // 0..3 -> k-group of 16 bytes
    const int l16  = lane & 15;    // row (A) / col (B) within 16
    const int wave = tid >> 6;     // 0..3
    const int wm = wave >> 1;      // wave row (2x2)
    const int wn = wave & 1;       // wave col
    const int bm = blockIdx.y;
    const int bn = blockIdx.x;

    const signed char* aG = xp + (size_t)(bm * BM) * K_DIM;
    const signed char* bG = wp + (size_t)(bn * BN) * K_DIM;

    // swizzled chunk offset for this lane's fragment reads (wave-uniform per t)
    const int csw = ((l16 >> 1) & 3);

    v4i acc[4][4];
#pragma unroll
    for (int i = 0; i < 4; i++)
#pragma unroll
        for (int j = 0; j < 4; j++) acc[i][j] = 0;

    for (int kk = 0; kk < K_DIM; kk += BK) {
        __syncthreads();  // protect LDS from previous iteration's readers
#pragma unroll
        for (int i = 0; i < 2; i++) {
            // linear chunk index: 512 chunks of 16B per operand tile
            int li  = i * 256 + tid;
            int row = li >> 2;                 // tile row (0..127)
            int c   = li & 3;                  // LDS chunk slot
            int g   = c ^ ((row >> 1) & 3);    // global chunk to place there
            g2lds16(aG + (size_t)row * K_DIM + kk + (g << 4), As + li * 16);
            g2lds16(bG + (size_t)row * K_DIM + kk + (g << 4), Bs + li * 16);
        }
        __syncthreads();  // compiler inserts s_waitcnt vmcnt(0) before barrier

        v4i af[4], bf[4];
#pragma unroll
        for (int t = 0; t < 4; t++) {
            af[t] = *(const v4i*)(As + (wm * 64 + t * 16 + l16) * BK
                                     + ((quad ^ csw) << 4));
            bf[t] = *(const v4i*)(Bs + (wn * 64 + t * 16 + l16) * BK
                                     + ((quad ^ csw) << 4));
        }
#pragma unroll
        for (int mt = 0; mt < 4; mt++)
#pragma unroll
            for (int nt = 0; nt < 4; nt++)
                acc[mt][nt] = __builtin_amdgcn_mfma_i32_16x16x64_i8(
                    af[mt], bf[nt], acc[mt][nt], 0, 0, 0);
    }

    // Epilogue: C/D layout (verified): col = lane&15, row = quad*4 + reg.
    const int s_base = bm * BM + wm * 64;
    const int n_base = bn * BN + wn * 64;
#pragma unroll
    for (int mt = 0; mt < 4; mt++) {
#pragma unroll
        for (int r = 0; r < 4; r++) {
            int s = s_base + mt * 16 + quad * 4 + r;
            float rs = sx[s] / sy[s];
            float* orow = out + (size_t)s * N_DIM;
#pragma unroll
            for (int nt = 0; nt < 4; nt++) {
                int n = n_base + nt * 16 + l16;
                float v = rintf((float)acc[mt][nt][r] * (rs * sw[n]));
                v = fminf(fmaxf(v, -128.f), 127.f);
                orow[n] = v;
            }
        }
    }
}

// ---------------------------------------------------------------------------
// Correctness fallback if the workspace is too small for packed operands.
__global__ void gemm_naive(const int* __restrict__ x, const int* __restrict__ w,
                           const float* __restrict__ sx, const float* __restrict__ sw,
                           const float* __restrict__ sy, float* __restrict__ out) {
    int n = blockIdx.x * blockDim.x + threadIdx.x;
    int s = blockIdx.y;
    const int4* xr = (const int4*)(x + (size_t)s * K_DIM);
    const int4* wr = (const int4*)(w + (size_t)n * K_DIM);
    int acc = 0;
    for (int k = 0; k < K_DIM / 4; k++) {
        int4 a = xr[k], b = wr[k];
        acc += a.x * b.x + a.y * b.y + a.z * b.z + a.w * b.w;
    }
    float v = rintf((float)acc * (sx[s] / sy[s] * sw[n]));
    out[(size_t)s * N_DIM + n] = fminf(fmaxf(v, -128.f), 127.f);
}

// ---------------------------------------------------------------------------
extern "C" void kernel_launch(void* const* d_in, const int* in_sizes, int n_in,
                              void* d_out, int out_size, void* d_ws, size_t ws_size,
                              hipStream_t stream) {
    const int*   x  = (const int*)d_in[0];     // [S, K] int8 values widened to int32
    const int*   wq = (const int*)d_in[1];     // [N, K]
    const float* sx = (const float*)d_in[2];   // [S]
    const float* sw = (const float*)d_in[3];   // [N]
    const float* sy = (const float*)d_in[4];   // [S]
    float* out = (float*)d_out;                // [S*N out_q] ++ [S scale_y], float32

    copy_sy<<<dim3((S_DIM + 255) / 256), dim3(256), 0, stream>>>(sy, out);

    const size_t need = (size_t)S_DIM * K_DIM + (size_t)N_DIM * K_DIM;  // 48 MiB
    if (ws_size >= need) {
        signed char* xp = (signed char*)d_ws;
        signed char* wp = xp + (size_t)S_DIM * K_DIM;
        pack_i8<<<dim3(S_DIM * K_DIM / 4 / 256), dim3(256), 0, stream>>>(
            x, (int*)xp, S_DIM * K_DIM / 4);
        pack_i8<<<dim3(N_DIM * K_DIM / 4 / 256), dim3(256), 0, stream>>>(
            wq, (int*)wp, N_DIM * K_DIM / 4);
        gemm_i8<<<dim3(N_DIM / BN, S_DIM / BM), dim3(256), 0, stream>>>(
            xp, wp, sx, sw, sy, out);
    } else {
        gemm_naive<<<dim3(N_DIM / 256, S_DIM), dim3(256), 0, stream>>>(
            x, wq, sx, sw, sy, out);
    }
}